// Round 3
// baseline (103.232 us; speedup 1.0000x reference)
//
#include <hip/hip_runtime.h>

#define BATCH 32
#define IC 16
#define OC 32
#define SI 32
#define KS 3
#define SO 30

#define ROWS 4                 // output rows per block band
#define XROWS (ROWS + KS - 1)  // 6 input rows staged
#define XCOLS 36               // 144 B rows: 16B-aligned float4 reads; cols 32..35 zero
#define NBANDS 8               // 30 rows in bands of 4 (last band rows 28..31, guarded)
#define RTOT (IC * KS * KS)    // 144 reduction length

// 512 threads = 8 waves/CU = 2 waves/SIMD (R2 had 1 wave/SIMD: latency exposed).
__global__ __launch_bounds__(512) void conv3x3_kernel(
    const float* __restrict__ x, const float* __restrict__ w,
    const float* __restrict__ bias, float* __restrict__ out)
{
    __shared__ __align__(16) float ws[RTOT][OC];          // [r][oc], 18 KB
    __shared__ __align__(16) float xs[IC][XROWS][XCOLS];  // 13.5 KB

    const int t    = threadIdx.x;
    const int blk  = blockIdx.x;
    const int band = blk & (NBANDS - 1);
    const int b    = blk >> 3;
    const int row0 = band * ROWS;

    // ---- stage weights transposed: ws[r][oc] = w[oc*144 + r] ----
    // LDS writes lane-consecutive (conflict-free); w is 18 KB, L2-hot.
    for (int idx = t; idx < RTOT * OC; idx += 512) {
        const int oc = idx & (OC - 1);
        const int r  = idx >> 5;
        ((float*)ws)[idx] = w[oc * RTOT + r];
    }

    // ---- stage input band (zero-fill pad cols 32..35 and rows >= 32) ----
    const float* xb = x + b * (IC * SI * SI);
    for (int idx = t; idx < IC * XROWS * XCOLS; idx += 512) {
        const int ic  = idx / (XROWS * XCOLS);
        const int rem = idx - ic * (XROWS * XCOLS);
        const int ii  = rem / XCOLS;
        const int jj  = rem - ii * XCOLS;
        const int gi  = row0 + ii;
        float v = 0.0f;
        if (gi < SI && jj < SI) v = xb[ic * SI * SI + gi * SI + jj];
        ((float*)xs)[idx] = v;
    }
    __syncthreads();

    // ---- per-thread 2-oc x 4-col register tile ----
    const int duo = t >> 5;        // 0..15 -> oc pair
    const int oc0 = duo * 2;
    const int tp  = t & 31;
    const int il  = tp >> 3;       // local output row 0..3
    const int c   = (tp & 7) * 4;  // col base 0,4,...,28

    float acc[2][4] = {{0.f}};     // [oo][jj]

    // unroll capped (R1 lesson: full unroll -> VGPR=256 + 790 MB spill)
    #pragma unroll 2
    for (int ic = 0; ic < IC; ++ic) {
        #pragma unroll
        for (int k1 = 0; k1 < KS; ++k1) {
            // 8-wide x window (cols c..c+7) via two aligned b128 reads; use 6
            const float4 xa = *reinterpret_cast<const float4*>(&xs[ic][il + k1][c]);
            const float4 xc = *reinterpret_cast<const float4*>(&xs[ic][il + k1][c + 4]);
            const float xw[8] = {xa.x, xa.y, xa.z, xa.w, xc.x, xc.y, xc.z, xc.w};
            #pragma unroll
            for (int k2 = 0; k2 < KS; ++k2) {
                // lanes 0-31 share one address -> LDS broadcast, conflict-free
                const float2 w2 =
                    *reinterpret_cast<const float2*>(&ws[ic * 9 + k1 * 3 + k2][oc0]);
                #pragma unroll
                for (int jj = 0; jj < 4; ++jj) {
                    acc[0][jj] = fmaf(w2.x, xw[k2 + jj], acc[0][jj]);
                    acc[1][jj] = fmaf(w2.y, xw[k2 + jj], acc[1][jj]);
                }
            }
        }
    }

    // ---- epilogue: bias + float2 stores (always 8B-aligned; float4 wouldn't be:
    // out rows are 120 B) ----
    const int i = row0 + il;
    if (i < SO) {
        #pragma unroll
        for (int oo = 0; oo < 2; ++oo) {
            const int oc = oc0 + oo;
            const float bs = bias[oc];
            float* orow = out + ((size_t)(b * OC + oc) * SO + i) * SO;
            // cols c, c+1 always valid (c <= 28)
            *reinterpret_cast<float2*>(&orow[c]) =
                make_float2(acc[oo][0] + bs, acc[oo][1] + bs);
            if (c + 3 < SO) {  // cols c+2, c+3 (skip only for c == 28)
                *reinterpret_cast<float2*>(&orow[c + 2]) =
                    make_float2(acc[oo][2] + bs, acc[oo][3] + bs);
            }
        }
    }
}

extern "C" void kernel_launch(void* const* d_in, const int* in_sizes, int n_in,
                              void* d_out, int out_size, void* d_ws, size_t ws_size,
                              hipStream_t stream) {
    const float* x    = (const float*)d_in[0];
    const float* w    = (const float*)d_in[1];
    const float* bias = (const float*)d_in[2];
    // d_in[3..5] (rows/cols/param_idx) encode a dense 3x3 valid conv — unused.
    float* out = (float*)d_out;

    conv3x3_kernel<<<dim3(BATCH * NBANDS), dim3(512), 0, stream>>>(x, w, bias, out);
}

// Round 4
// 97.532 us; speedup vs baseline: 1.0584x; 1.0584x over previous
//
#include <hip/hip_runtime.h>

#define BATCH 32
#define IC 16
#define OC 32
#define SI 32
#define KS 3
#define SO 30

#define ROWS 4                 // output rows per band
#define XROWS (ROWS + KS - 1)  // 6 input rows staged
#define XCOLS 36               // 144 B rows; cols 32..35 zero pad
#define NBANDS 8
#define WPT (IC * KS * KS)     // 144 weights per oc

// grid: batch(32) x ocgroup(2) x band(8) = 512 blocks x 256 thr
//   -> 2 blocks/CU, 8 waves/CU, 2 waves/SIMD.
// Each wave owns 4 oc (wave-uniform -> weights via scalar s_load, no LDS).
__global__ __launch_bounds__(256) void conv3x3_kernel(
    const float* __restrict__ x, const float* __restrict__ w,
    const float* __restrict__ bias, float* __restrict__ out)
{
    __shared__ __align__(16) float xs[IC][XROWS][XCOLS];  // 13.8 KB, x only

    const int t    = threadIdx.x;
    const int blk  = blockIdx.x;
    const int band = blk & (NBANDS - 1);
    const int g    = (blk >> 3) & 1;   // oc half
    const int b    = blk >> 4;         // batch
    const int row0 = band * ROWS;

    // ---- stage input band (zero-fill pad cols / out-of-range rows) ----
    const float* xb = x + b * (IC * SI * SI);
    for (int idx = t; idx < IC * XROWS * XCOLS; idx += 256) {
        const int ic  = idx / (XROWS * XCOLS);
        const int rem = idx - ic * (XROWS * XCOLS);
        const int ii  = rem / XCOLS;
        const int jj  = rem - ii * XCOLS;
        const int gi  = row0 + ii;
        float v = 0.0f;
        if (gi < SI && jj < SI) v = xb[ic * SI * SI + gi * SI + jj];
        ((float*)xs)[idx] = v;
    }
    __syncthreads();

    // ---- wave-uniform oc quad: weights come in through SGPRs ----
    const int wvid = __builtin_amdgcn_readfirstlane(t >> 6);  // 0..3, uniform
    const int oc0  = g * 16 + wvid * 4;
    const float* __restrict__ wq = w + oc0 * WPT;             // uniform base

    const int l  = t & 63;
    const int il = l >> 4;        // local row 0..3
    const int c  = (l & 15) * 2;  // col base 0,2,...,30 (c==30 is dead, reads pad)

    float acc[4][2] = {{0.f}};    // [oo][jj]

    #pragma unroll 2
    for (int ic = 0; ic < IC; ++ic) {
        #pragma unroll
        for (int k1 = 0; k1 < KS; ++k1) {
            // 4-wide x window (cols c..c+3), two aligned b64 reads
            const float2 xa = *reinterpret_cast<const float2*>(&xs[ic][il + k1][c]);
            const float2 xc = *reinterpret_cast<const float2*>(&xs[ic][il + k1][c + 2]);
            const float xw[4] = {xa.x, xa.y, xc.x, xc.y};
            #pragma unroll
            for (int k2 = 0; k2 < KS; ++k2) {
                #pragma unroll
                for (int oo = 0; oo < 4; ++oo) {
                    // uniform address -> s_load; SGPR operand in v_fma is legal
                    const float wv = wq[oo * WPT + ic * 9 + k1 * 3 + k2];
                    acc[oo][0] = fmaf(wv, xw[k2],     acc[oo][0]);
                    acc[oo][1] = fmaf(wv, xw[k2 + 1], acc[oo][1]);
                }
            }
        }
    }

    // ---- epilogue: bias + float2 store (8B aligned, c even) ----
    const int i = row0 + il;
    if (i < SO && c < SO) {       // c==30 lane has no valid cols
        #pragma unroll
        for (int oo = 0; oo < 4; ++oo) {
            const int oc = oc0 + oo;
            const float bs = bias[oc];
            float* orow = out + ((size_t)(b * OC + oc) * SO + i) * SO;
            *reinterpret_cast<float2*>(&orow[c]) =
                make_float2(acc[oo][0] + bs, acc[oo][1] + bs);
        }
    }
}

extern "C" void kernel_launch(void* const* d_in, const int* in_sizes, int n_in,
                              void* d_out, int out_size, void* d_ws, size_t ws_size,
                              hipStream_t stream) {
    const float* x    = (const float*)d_in[0];
    const float* w    = (const float*)d_in[1];
    const float* bias = (const float*)d_in[2];
    // d_in[3..5] (rows/cols/param_idx) encode a dense 3x3 valid conv — unused.
    float* out = (float*)d_out;

    conv3x3_kernel<<<dim3(BATCH * 2 * NBANDS), dim3(256), 0, stream>>>(x, w, bias, out);
}

// Round 5
// 94.515 us; speedup vs baseline: 1.0922x; 1.0319x over previous
//
#include <hip/hip_runtime.h>

#define BATCH 32
#define IC 16
#define OC 32
#define SI 32
#define KS 3
#define SO 30

#define ROWS 4                 // output rows per band
#define XROWS (ROWS + KS - 1)  // 6 input rows staged
#define XCOLS 36               // 144 B rows = 9 float4; cols 32..35 zero pad
#define NBANDS 8
#define WPT (IC * KS * KS)     // 144 weights per oc
#define NROW (IC * XROWS)      // 96 staged LDS rows
#define NV4  (NROW * 9)        // 864 float4 slots (8 data + 1 pad per row)

// grid: batch(32) x band(8) = 256 blocks x 512 thr -> exactly 1 block/CU,
// 8 waves/CU = 2 waves/SIMD. Wave w owns oc quad w*4.. (uniform -> s_load
// weights, zero LDS/DS-pipe cost for w). x staged once per (b,band) — R4
// staged it twice (per oc-half).
__global__ __launch_bounds__(512) void conv3x3_kernel(
    const float* __restrict__ x, const float* __restrict__ w,
    const float* __restrict__ bias, float* __restrict__ out)
{
    __shared__ __align__(16) float xs[IC][XROWS][XCOLS];  // 13.8 KB

    const int t    = threadIdx.x;
    const int blk  = blockIdx.x;
    const int band = blk & (NBANDS - 1);
    const int b    = blk >> 3;
    const int row0 = band * ROWS;

    // ---- stage input band, float4-vectorized ----
    // LDS row stride 144 B (16B-aligned); slot q==8 is the 16 B zero pad.
    const float* xb = x + b * (IC * SI * SI);
    for (int idx = t; idx < NV4; idx += 512) {
        const int r  = idx / 9;        // LDS row 0..95 = ic*6 + ii
        const int q  = idx - r * 9;    // float4 slot 0..8
        const int ic = r / XROWS;
        const int ii = r - ic * XROWS;
        const int gi = row0 + ii;
        float4 v = make_float4(0.f, 0.f, 0.f, 0.f);
        if (q < 8 && gi < SI)
            v = *reinterpret_cast<const float4*>(&xb[ic * SI * SI + gi * SI + q * 4]);
        *reinterpret_cast<float4*>(&xs[ic][ii][q * 4]) = v;
    }
    __syncthreads();

    // ---- wave-uniform oc quad: weights through SGPRs ----
    const int wvid = __builtin_amdgcn_readfirstlane(t >> 6);  // 0..7, uniform
    const int oc0  = wvid * 4;
    const float* __restrict__ wq = w + oc0 * WPT;             // uniform base

    const int l  = t & 63;
    const int il = l >> 4;        // local row 0..3
    const int c  = (l & 15) * 2;  // col base 0,2,...,30 (c==30 lane reads pad, no store)

    float acc[4][2] = {{0.f}};    // [oo][jj]

    // unroll capped (R1 lesson: full unroll -> VGPR=256 + spill)
    #pragma unroll 2
    for (int ic = 0; ic < IC; ++ic) {
        #pragma unroll
        for (int k1 = 0; k1 < KS; ++k1) {
            // 4-wide x window (cols c..c+3), two aligned b64 reads
            const float2 xa = *reinterpret_cast<const float2*>(&xs[ic][il + k1][c]);
            const float2 xc = *reinterpret_cast<const float2*>(&xs[ic][il + k1][c + 2]);
            const float xw[4] = {xa.x, xa.y, xc.x, xc.y};
            #pragma unroll
            for (int k2 = 0; k2 < KS; ++k2) {
                #pragma unroll
                for (int oo = 0; oo < 4; ++oo) {
                    const float wv = wq[oo * WPT + ic * 9 + k1 * 3 + k2]; // s_load
                    acc[oo][0] = fmaf(wv, xw[k2],     acc[oo][0]);
                    acc[oo][1] = fmaf(wv, xw[k2 + 1], acc[oo][1]);
                }
            }
        }
    }

    // ---- epilogue: bias + float2 store (8B aligned, c even) ----
    const int i = row0 + il;
    if (i < SO && c < SO) {
        #pragma unroll
        for (int oo = 0; oo < 4; ++oo) {
            const int oc = oc0 + oo;
            const float bs = bias[oc];
            float* orow = out + ((size_t)(b * OC + oc) * SO + i) * SO;
            *reinterpret_cast<float2*>(&orow[c]) =
                make_float2(acc[oo][0] + bs, acc[oo][1] + bs);
        }
    }
}

extern "C" void kernel_launch(void* const* d_in, const int* in_sizes, int n_in,
                              void* d_out, int out_size, void* d_ws, size_t ws_size,
                              hipStream_t stream) {
    const float* x    = (const float*)d_in[0];
    const float* w    = (const float*)d_in[1];
    const float* bias = (const float*)d_in[2];
    // d_in[3..5] (rows/cols/param_idx) encode a dense 3x3 valid conv — unused.
    float* out = (float*)d_out;

    conv3x3_kernel<<<dim3(BATCH * NBANDS), dim3(512), 0, stream>>>(x, w, bias, out);
}